// Round 7
// baseline (329.331 us; speedup 1.0000x reference)
//
#include <hip/hip_runtime.h>

#define B_ 256
#define T_ 512
#define N_ 128

typedef _Float16 half2v  __attribute__((ext_vector_type(2)));  // fdot2 operand type
typedef float    float2v __attribute__((ext_vector_type(2)));

// pack two f32 -> f16x2 (v_cvt_pkrtz_f16_f32), bit_cast to fdot2 operand type
__device__ __forceinline__ half2v pk16(float a, float b) {
    return __builtin_bit_cast(half2v, __builtin_amdgcn_cvt_pkrtz(a, b));
}
__device__ __forceinline__ int readlane_i(int v, int k) {
    return __builtin_amdgcn_readlane(v, k);
}
__device__ __forceinline__ float readlane_f(float v, int k) {
    return __int_as_float(__builtin_amdgcn_readlane(__float_as_int(v), k));
}

// ONE WAVE PER BATCH — zero barriers, zero LDS on the recursion chain.
// R3 vs R6 showed the 4-wave design is bound by the ds_write/barrier/ds_read
// combine chain (~650 cyc/step), not by VALU issue; this removes it.
// Lane l owns output states j0=2l, j1=2l+1 and holds the FULL exp(transition)
// table as f16 i-pairs: ej0[64], ej1[64] (128 VGPRs; fine at 1 wave/SIMD).
// q is replicated per-lane as packed f16 {q_2l, q_2l+1}; per step the wave
// does 64 v_readlane + 128 v_dot2_f32_f16 into 4-deep accumulator trees.
// Per-step rescale by state-0's value (readlane, rcp started early);
// log(scale) accumulates in Macc. Score + logZ reduce in-wave at the end.
__global__ __launch_bounds__(64, 1) void crf_fused_kernel(
    const float* __restrict__ lp,      // [B,T,N]
    const float* __restrict__ trans,   // [N,N]
    const float* __restrict__ startt,  // [N]
    const float* __restrict__ endt,    // [N]
    const int*   __restrict__ target,  // [B,T]
    const int*   __restrict__ lengths, // [B]
    float*       __restrict__ out)     // [B]
{
    const int b  = blockIdx.x;
    const int l  = threadIdx.x;        // lane 0..63
    const int j0 = 2 * l;

    // full transition table, f16 pairs over i: ej0[m] = {e(2m,j0), e(2m+1,j0)}
    half2v ej0[64], ej1[64];
    #pragma unroll
    for (int m = 0; m < 64; ++m) {
        float2v te0 = *(const float2v*)(trans + (2 * m)     * N_ + j0);
        float2v te1 = *(const float2v*)(trans + (2 * m + 1) * N_ + j0);
        ej0[m] = pk16(__expf(te0.x), __expf(te1.x));
        ej1[m] = pk16(__expf(te0.y), __expf(te1.y));
    }

    const float* lpb = lp + (size_t)b * (T_ * N_);
    const int len = lengths[b];        // in [256, 512]

    // t = 0 init, rescaled by state 0
    float v0, v1, Macc;
    {
        float2v st2 = *(const float2v*)(startt + j0);
        float2v e0r = *(const float2v*)(lpb + j0);
        float a = __expf(st2.x + e0r.x);
        float c = __expf(st2.y + e0r.y);
        float sc  = readlane_f(a, 0);
        float isc = __builtin_amdgcn_rcpf(sc);
        v0 = a * isc; v1 = c * isc;
        Macc = __logf(sc);
    }
    half2v qp = pk16(v0, v1);

    // emission prefetch pipeline, distance 2 (len >= 256: rows 1,2 valid)
    float2v cur = *(const float2v*)(lpb + N_ + j0);
    float2v nx  = *(const float2v*)(lpb + 2 * N_ + j0);

    for (int t = 1; t < len; ++t) {
        const int tp = (t + 2 < T_) ? t + 2 : T_ - 1;   // clamped, in-bounds
        float2v nn = *(const float2v*)(lpb + (size_t)tp * N_ + j0);

        float eexp0 = __expf(cur.x);
        float eexp1 = __expf(cur.y);
        float rl0e  = readlane_f(eexp0, 0);   // early: off the critical chain

        // full contraction: 64 readlane + 128 fdot2, 4 accum chains per j
        const int qpi = __builtin_bit_cast(int, qp);
        float A0[4] = {0.f, 0.f, 0.f, 0.f};
        float A1[4] = {0.f, 0.f, 0.f, 0.f};
        #pragma unroll
        for (int c = 0; c < 64; c += 8) {
            int s[8];
            #pragma unroll
            for (int r = 0; r < 8; ++r)
                s[r] = readlane_i(qpi, c + r);
            #pragma unroll
            for (int r = 0; r < 8; ++r) {
                half2v h = __builtin_bit_cast(half2v, s[r]);
                A0[r & 3] = __builtin_amdgcn_fdot2(h, ej0[c + r], A0[r & 3], false);
                A1[r & 3] = __builtin_amdgcn_fdot2(h, ej1[c + r], A1[r & 3], false);
            }
        }
        float sx = (A0[0] + A0[1]) + (A0[2] + A0[3]);
        float sy = (A1[0] + A1[1]) + (A1[2] + A1[3]);

        // rescale by state 0: sc == (sx*eexp0) at lane 0, computed via the
        // early readlanes so rcp overlaps the eexp multiplies
        float sc  = readlane_f(sx, 0) * rl0e;
        float isc = __builtin_amdgcn_rcpf(sc);
        v0 = (sx * eexp0) * isc;
        v1 = (sy * eexp1) * isc;
        qp = pk16(v0, v1);
        Macc += __logf(sc);

        cur = nx; nx = nn;
    }

    // ---- log Z (in-wave reduction) ----
    float2v en2 = *(const float2v*)(endt + j0);
    float f = v0 * __expf(en2.x) + v1 * __expf(en2.y);
    #pragma unroll
    for (int off = 32; off > 0; off >>= 1) f += __shfl_xor(f, off);
    float logz = Macc + __logf(f);

    // ---- path score (gathers, in-wave) ----
    const int* tg = target + b * T_;
    float acc = 0.f;
    for (int t = l; t < len; t += 64) {
        int c = tg[t];
        acc += lpb[t * N_ + c];
        if (t + 1 < len) acc += trans[c * N_ + tg[t + 1]];
    }
    #pragma unroll
    for (int off = 32; off > 0; off >>= 1) acc += __shfl_xor(acc, off);

    if (l == 0) {
        out[b] = acc + startt[tg[0]] + endt[tg[len - 1]] - logz;
    }
}

extern "C" void kernel_launch(void* const* d_in, const int* in_sizes, int n_in,
                              void* d_out, int out_size, void* d_ws, size_t ws_size,
                              hipStream_t stream) {
    const float* lp     = (const float*)d_in[0];
    const float* trans  = (const float*)d_in[1];
    const float* st     = (const float*)d_in[2];
    const float* en     = (const float*)d_in[3];
    const int*   target = (const int*)d_in[4];
    const int*   lens   = (const int*)d_in[5];
    float* out = (float*)d_out;

    crf_fused_kernel<<<B_, 64, 0, stream>>>(lp, trans, st, en, target, lens, out);
}

// Round 8
// 324.312 us; speedup vs baseline: 1.0155x; 1.0155x over previous
//
#include <hip/hip_runtime.h>

#define B_ 256
#define T_ 512
#define N_ 128

typedef _Float16 half2v  __attribute__((ext_vector_type(2)));  // fdot2 operand type
typedef float    float2v __attribute__((ext_vector_type(2)));

// pack two f32 -> f16x2 (v_cvt_pkrtz_f16_f32), bit_cast to fdot2 operand type
__device__ __forceinline__ half2v pk16(float a, float b) {
    return __builtin_bit_cast(half2v, __builtin_amdgcn_cvt_pkrtz(a, b));
}
__device__ __forceinline__ int readlane_i(int v, int k) {
    return __builtin_amdgcn_readlane(v, k);
}
__device__ __forceinline__ float readlane_f(float v, int k) {
    return __int_as_float(__builtin_amdgcn_readlane(__float_as_int(v), k));
}

// ONE WAVE PER BATCH — zero barriers, zero LDS on the recursion chain.
// R7 showed the structure works but the compiler placed the 128-VGPR
// exp(transition) table in AGPRs (VGPR_Count=80), adding a v_accvgpr_read
// per fdot2 operand. amdgpu_waves_per_eu(1,1) grants the full 256-VGPR
// arch budget so the table stays in VGPRs.
// Lane l owns output states j0=2l, j1=2l+1; per step: 64 v_readlane +
// 128 v_dot2_f32_f16 (4 accumulator chains per output).
// Per-step rescale by readlane(A0[0],0)*eexp0[0] — a PARTIAL sum, available
// earlier than the full tree; exact because Macc += log(sc) tracks any
// positive scale. Score + logZ reduce in-wave at the end.
__global__ __attribute__((amdgpu_flat_work_group_size(64, 64),
                          amdgpu_waves_per_eu(1, 1)))
void crf_fused_kernel(
    const float* __restrict__ lp,      // [B,T,N]
    const float* __restrict__ trans,   // [N,N]
    const float* __restrict__ startt,  // [N]
    const float* __restrict__ endt,    // [N]
    const int*   __restrict__ target,  // [B,T]
    const int*   __restrict__ lengths, // [B]
    float*       __restrict__ out)     // [B]
{
    const int b  = blockIdx.x;
    const int l  = threadIdx.x;        // lane 0..63
    const int j0 = 2 * l;

    // full transition table, f16 pairs over i: ej0[m] = {e(2m,j0), e(2m+1,j0)}
    half2v ej0[64], ej1[64];
    #pragma unroll
    for (int m = 0; m < 64; ++m) {
        float2v te0 = *(const float2v*)(trans + (2 * m)     * N_ + j0);
        float2v te1 = *(const float2v*)(trans + (2 * m + 1) * N_ + j0);
        ej0[m] = pk16(__expf(te0.x), __expf(te1.x));
        ej1[m] = pk16(__expf(te0.y), __expf(te1.y));
    }

    const float* lpb = lp + (size_t)b * (T_ * N_);
    const int len = lengths[b];        // in [256, 512]

    // t = 0 init, rescaled by state 0
    float v0, v1, Macc;
    {
        float2v st2 = *(const float2v*)(startt + j0);
        float2v e0r = *(const float2v*)(lpb + j0);
        float a = __expf(st2.x + e0r.x);
        float c = __expf(st2.y + e0r.y);
        float sc  = readlane_f(a, 0);
        float isc = __builtin_amdgcn_rcpf(sc);
        v0 = a * isc; v1 = c * isc;
        Macc = __logf(sc);
    }
    half2v qp = pk16(v0, v1);

    // emission prefetch pipeline, distance 2 (len >= 256: rows 1,2 valid)
    float2v cur = *(const float2v*)(lpb + N_ + j0);
    float2v nx  = *(const float2v*)(lpb + 2 * N_ + j0);

    for (int t = 1; t < len; ++t) {
        const int tp = (t + 2 < T_) ? t + 2 : T_ - 1;   // clamped, in-bounds
        float2v nn = *(const float2v*)(lpb + (size_t)tp * N_ + j0);

        float eexp0 = __expf(cur.x);
        float eexp1 = __expf(cur.y);
        float rl0e  = readlane_f(eexp0, 0);   // early: off the critical chain

        // full contraction: 64 readlane + 128 fdot2, 4 accum chains per j
        const int qpi = __builtin_bit_cast(int, qp);
        float A0[4] = {0.f, 0.f, 0.f, 0.f};
        float A1[4] = {0.f, 0.f, 0.f, 0.f};
        #pragma unroll
        for (int c = 0; c < 64; c += 8) {
            int s[8];
            #pragma unroll
            for (int r = 0; r < 8; ++r)
                s[r] = readlane_i(qpi, c + r);
            #pragma unroll
            for (int r = 0; r < 8; ++r) {
                half2v h = __builtin_bit_cast(half2v, s[r]);
                A0[r & 3] = __builtin_amdgcn_fdot2(h, ej0[c + r], A0[r & 3], false);
                A1[r & 3] = __builtin_amdgcn_fdot2(h, ej1[c + r], A1[r & 3], false);
            }
        }

        // scale from a PARTIAL accumulator (state 0, chains 0): available
        // before the full reduction trees finish; exact via Macc tracking.
        float scp = readlane_f(A0[0], 0) * rl0e;
        float isc = __builtin_amdgcn_rcpf(scp);
        Macc += __logf(scp);                   // off-chain

        float sx = (A0[0] + A0[1]) + (A0[2] + A0[3]);
        float sy = (A1[0] + A1[1]) + (A1[2] + A1[3]);

        float f0 = eexp0 * isc;                // overlaps the trees
        float f1 = eexp1 * isc;
        v0 = sx * f0;
        v1 = sy * f1;
        qp = pk16(v0, v1);

        cur = nx; nx = nn;
    }

    // ---- log Z (in-wave reduction) ----
    float2v en2 = *(const float2v*)(endt + j0);
    float f = v0 * __expf(en2.x) + v1 * __expf(en2.y);
    #pragma unroll
    for (int off = 32; off > 0; off >>= 1) f += __shfl_xor(f, off);
    float logz = Macc + __logf(f);

    // ---- path score (gathers, in-wave) ----
    const int* tg = target + b * T_;
    float acc = 0.f;
    for (int t = l; t < len; t += 64) {
        int c = tg[t];
        acc += lpb[t * N_ + c];
        if (t + 1 < len) acc += trans[c * N_ + tg[t + 1]];
    }
    #pragma unroll
    for (int off = 32; off > 0; off >>= 1) acc += __shfl_xor(acc, off);

    if (l == 0) {
        out[b] = acc + startt[tg[0]] + endt[tg[len - 1]] - logz;
    }
}

extern "C" void kernel_launch(void* const* d_in, const int* in_sizes, int n_in,
                              void* d_out, int out_size, void* d_ws, size_t ws_size,
                              hipStream_t stream) {
    const float* lp     = (const float*)d_in[0];
    const float* trans  = (const float*)d_in[1];
    const float* st     = (const float*)d_in[2];
    const float* en     = (const float*)d_in[3];
    const int*   target = (const int*)d_in[4];
    const int*   lens   = (const int*)d_in[5];
    float* out = (float*)d_out;

    crf_fused_kernel<<<B_, 64, 0, stream>>>(lp, trans, st, en, target, lens, out);
}